// Round 9
// baseline (640.090 us; speedup 1.0000x reference)
//
#include <hip/hip_runtime.h>

// Problem shape (fixed by setup_inputs):
//   x: [B=32, S=2048, F=128] fp32, window W=16
//   out: [B, S, W, F] fp32, out[b,i,w,f] = (i+w < S) ? x[b,i+w,f] : 0
//
// In float4 units, output index o:
//   chunk = o>>9 (= b*2048+i), r = o&511, src = (chunk<<5)+r,
//   valid iff (chunk&2047) + (r>>5) < 2048.
//
// DIAGNOSTIC ROUND: REPS=2 makes our dispatch ~2x kernel time so it ranks in
// the rocprof top-5 (fills sit at ~340 us and hide anything smaller). The
// memory clobber between reps prevents load/store elimination. Revert REPS=1
// next round.
//
//  - native clang ext_vector float4 (floatx4) so __builtin_nontemporal_store
//    accepts the pointer (HIP's float4 class does not compile with it).
//  - block-contiguous mapping: block g owns float4 [g*8192, (g+1)*8192)
//    (16 output chunks); its x read-set is ~16 KB -> L1-resident reuse.
//  - 32-bit index arithmetic (max index 33.5M < 2^31).
//  - nontemporal stores: keep the 537 MB write stream from evicting x in L2.

typedef float floatx4 __attribute__((ext_vector_type(4)));

#define NTHR 256u
#define PER_BLOCK 8192u          // float4 per block = 16 chunks
#define NBLK 4096u               // 4096*8192 = 33,554,432 = total float4
#define REPS 2                   // DIAGNOSTIC ONLY

__global__ __launch_bounds__(256) void WindowingLayer_22084721836441_kernel(
    const floatx4* __restrict__ x, floatx4* __restrict__ out) {
    unsigned base = blockIdx.x * PER_BLOCK + threadIdx.x;
    for (int rep = 0; rep < REPS; ++rep) {
#pragma unroll
        for (unsigned t = 0; t < 32; t += 8) {
            unsigned o[8];
            floatx4 v[8];
#pragma unroll
            for (int k = 0; k < 8; ++k) {
                o[k] = base + (t + (unsigned)k) * NTHR;
                unsigned chunk = o[k] >> 9;       // b*2048 + i
                unsigned r = o[k] & 511u;
                unsigned row = (chunk & 2047u) + (r >> 5);
                v[k] = (floatx4)(0.f, 0.f, 0.f, 0.f);
                if (row < 2048u) {
                    v[k] = x[(chunk << 5) + r];
                }
            }
#pragma unroll
            for (int k = 0; k < 8; ++k) {
                __builtin_nontemporal_store(v[k], &out[o[k]]);
            }
        }
        asm volatile("" ::: "memory");  // keep rep 2 honest (no CSE of loads/stores)
    }
}

extern "C" void kernel_launch(void* const* d_in, const int* in_sizes, int n_in,
                              void* d_out, int out_size, void* d_ws, size_t ws_size,
                              hipStream_t stream) {
    const floatx4* x = (const floatx4*)d_in[0];
    floatx4* out = (floatx4*)d_out;
    WindowingLayer_22084721836441_kernel<<<NBLK, NTHR, 0, stream>>>(x, out);
}

// Round 13
// 538.017 us; speedup vs baseline: 1.1897x; 1.1897x over previous
//
#include <hip/hip_runtime.h>

// Problem shape (fixed by setup_inputs):
//   x: [B=32, S=2048, F=128] fp32, window W=16
//   out: [B, S, W, F] fp32, out[b,i,w,f] = (i+w < S) ? x[b,i+w,f] : 0
//
// out chunk (b,i) = 512 float4, a contiguous copy of x rows i..i+15 (zero
// past row S). This version: each block owns NC=32 consecutive chunks of one
// batch, stages the NC+15=47 source rows (23.5 KB) into LDS once, then emits
// a PURE contiguous nontemporal store stream (fill-like: the harness fills
// sustain 6.2 TB/s with zero loads; our previous kernels interleaved a
// global-load stream and sat at ~3.6 TB/s effective).
//
// Mapping (float4 units): block g: b = g>>6, i0 = (g&63)*32.
//   o_local in [0,16384): cl = o_local>>9, r = o_local&511
//   source = lds[(cl + (r>>5))*32 + (r&31)]  == x[b, i0+cl+(r>>5), :]
//   staging zeroes rows >= 2048, which yields the tail zero-padding for free.

typedef float floatx4 __attribute__((ext_vector_type(4)));

#define NTHR 256
#define NC 32                 // chunks (window positions) per block
#define ROWS (NC + 15)        // 47 staged x rows
#define BLK_F4 (NC * 512)     // 16384 output float4 per block

__global__ __launch_bounds__(NTHR) void WindowingLayer_22084721836441_kernel(
    const floatx4* __restrict__ x, floatx4* __restrict__ out) {
    __shared__ floatx4 lds[48 * 32];            // 48 rows padded, 24 KB
    const int b  = blockIdx.x >> 6;
    const int i0 = (blockIdx.x & 63) * NC;
    const int t  = threadIdx.x;

    // ---- stage 47 rows (1504 float4), zero past row 2048 ----
    const floatx4* xs = x + (((b << 11) + i0) << 5);   // (b*2048 + i0) * 32
    const int rows_left = 2048 - i0;                    // >= 32 always
    const int valid_f4 = (rows_left < ROWS ? rows_left : ROWS) << 5;
    for (int idx = t; idx < ROWS * 32; idx += NTHR) {
        floatx4 v = (floatx4)(0.f, 0.f, 0.f, 0.f);
        if (idx < valid_f4) v = xs[idx];
        lds[idx] = v;
    }
    __syncthreads();

    // ---- pure store stream: 16384 float4, lane-contiguous ----
    floatx4* ob = out + (size_t)blockIdx.x * BLK_F4;
#pragma unroll 1
    for (int j = 0; j < 64; j += 8) {
        floatx4 v[8];
#pragma unroll
        for (int k = 0; k < 8; ++k) {
            int ol = t + (j + k) * NTHR;
            int cl = ol >> 9;
            int r  = ol & 511;
            v[k] = lds[((cl + (r >> 5)) << 5) + (r & 31)];
        }
#pragma unroll
        for (int k = 0; k < 8; ++k) {
            __builtin_nontemporal_store(v[k], &ob[t + (j + k) * NTHR]);
        }
    }
}

extern "C" void kernel_launch(void* const* d_in, const int* in_sizes, int n_in,
                              void* d_out, int out_size, void* d_ws, size_t ws_size,
                              hipStream_t stream) {
    const floatx4* x = (const floatx4*)d_in[0];
    floatx4* out = (floatx4*)d_out;
    // 32 batches * 64 blocks/batch = 2048 blocks, each 16384 float4
    WindowingLayer_22084721836441_kernel<<<2048, NTHR, 0, stream>>>(x, out);
}